// Round 2
// baseline (166700.012 us; speedup 1.0000x reference)
//
#include <hip/hip_runtime.h>
#include <math.h>

// Problem constants (match reference)
#define B_    64
#define T_    2048
#define DIN   256
#define DH    256
#define DC    256
#define DOUT  256

__device__ __forceinline__ float sigmoidf_(float x) {
    return 1.0f / (1.0f + __expf(-x));
}

__device__ __forceinline__ float tanhf_(float x) {
    float ax = fabsf(x);
    float e  = __expf(-2.0f * ax);
    float t  = (1.0f - e) / (1.0f + e);
    return copysignf(t, x);
}

// ---------------------------------------------------------------------------
// Recurrent kernel: 64 WGs (1 per batch) x 1024 threads (16 waves).
// ALL gate weights live in VGPRs: thread (kq, n3) owns W[kq*128 .. +128, n3]
// for the 3 gate matrices -> wf/wi/wo[128] = 384 floats/thread.
// Weights are fetched from L2 exactly once (startup), killing the per-step
// 1.8 MB/CU L2 stream that bounded round 1 (13.7 us/step -> VALU-bound).
// Output projection is DEFERRED: h_t is written to d_out, a second kernel
// applies sigmoid(h @ Wout + bout) in place on all 256 CUs.
// ---------------------------------------------------------------------------
__global__ __launch_bounds__(1024, 1) void lstm_rec(
    const float* __restrict__ x,  const float* __restrict__ h0,
    const float* __restrict__ c0, const float* __restrict__ Wf,
    const float* __restrict__ bf, const float* __restrict__ Wi,
    const float* __restrict__ bi, const float* __restrict__ Wo,
    const float* __restrict__ bo, const int* __restrict__ Np,
    float* __restrict__ out, int xT)
{
    const int b   = blockIdx.x;
    const int tid = threadIdx.x;
    const int kq  = tid >> 8;      // k-quarter 0..3 (4 waves each)
    const int n3  = tid & 255;     // gate column 0..255
    const int N   = *Np;

    __shared__ __align__(16) float comb[DIN + DH];   // [x_t | h_t]
    __shared__ float part[3][4][DC];                 // 12 KiB partials

    // ---- stage weights into registers (one-time, coalesced over n3) ----
    float wf[128], wi[128], wo[128];
    {
        const int kbase = kq * 128;
        #pragma unroll
        for (int k = 0; k < 128; ++k) {
            wf[k] = Wf[(size_t)(kbase + k) * DC + n3];
            wi[k] = Wi[(size_t)(kbase + k) * DC + n3];
            wo[k] = Wo[(size_t)(kbase + k) * DC + n3];
        }
    }

    // state owned by kq==0 threads (thread n3 owns column n3)
    float c = 0.f, h = 0.f, bfr = 0.f, bir = 0.f, bor = 0.f;
    if (kq == 0) {
        c   = c0[b * DC + n3];
        h   = h0[b * DH + n3];
        bfr = bf[n3]; bir = bi[n3]; bor = bo[n3];
        comb[DIN + n3] = h;
        comb[n3]       = x[((size_t)b * xT) * DIN + n3];
    }
    __syncthreads();

    const size_t xbase = (size_t)b * xT * DIN;

    for (int t = 0; t < N; ++t) {
        // prefetch next x row early (kq==1 waves), overlaps the FMA loop
        float xv = 0.f;
        if (kq == 1 && t + 1 < N)
            xv = x[xbase + (size_t)(t + 1) * DIN + n3];

        // ---- partial dots over this thread's 128 k values ----
        float af = 0.f, ai = 0.f, ao = 0.f;
        const float* cb = &comb[kq * 128];
        #pragma unroll
        for (int k4 = 0; k4 < 32; ++k4) {
            const float4 cv = *(const float4*)(cb + 4 * k4);  // LDS broadcast b128
            af += cv.x * wf[4*k4+0]; ai += cv.x * wi[4*k4+0]; ao += cv.x * wo[4*k4+0];
            af += cv.y * wf[4*k4+1]; ai += cv.y * wi[4*k4+1]; ao += cv.y * wo[4*k4+1];
            af += cv.z * wf[4*k4+2]; ai += cv.z * wi[4*k4+2]; ao += cv.z * wo[4*k4+2];
            af += cv.w * wf[4*k4+3]; ai += cv.w * wi[4*k4+3]; ao += cv.w * wo[4*k4+3];
        }
        part[0][kq][n3] = af;
        part[1][kq][n3] = ai;
        part[2][kq][n3] = ao;
        __syncthreads();

        // ---- gate math: thread n3 (kq==0) owns column n3 ----
        if (kq == 0) {
            float fp = bfr + part[0][0][n3] + part[0][1][n3] + part[0][2][n3] + part[0][3][n3];
            float ip = bir + part[1][0][n3] + part[1][1][n3] + part[1][2][n3] + part[1][3][n3];
            float op = bor + part[2][0][n3] + part[2][1][n3] + part[2][2][n3] + part[2][3][n3];
            const float f = sigmoidf_(fp);
            const float i = sigmoidf_(ip);
            const float z = tanhf_(ip);          // pre_i reused, per reference
            const float o = sigmoidf_(op);
            c = c * f + z * i;
            h = tanhf_(c) * o;
            comb[DIN + n3] = h;                                  // publish h_{t+1}
            out[((size_t)b * N + t) * DOUT + n3] = h;            // raw h; post kernel projects
        } else if (kq == 1 && t + 1 < N) {
            comb[n3] = xv;                                       // publish x_{t+1}
        }
        __syncthreads();
    }

    // finals: d_out = [ outs (B*N*DOUT) | h_final (B*DH) | c_final (B*DC) ]
    if (kq == 0) {
        float* hf = out + (size_t)B_ * N * DOUT;
        float* cf = hf + (size_t)B_ * DH;
        hf[b * DH + n3] = h;
        cf[b * DC + n3] = c;
    }
}

// ---------------------------------------------------------------------------
// Output projection, in place on d_out: out[r,:] = sigmoid(h[r,:] @ Wout + bout)
// 64 rows per WG staged in LDS (64 KB -> 2 WGs/CU), 64 accumulators/thread,
// 16 FMA per LDS b128 broadcast. ~17 GFLOP on 256 CUs -> ~120 us.
// ---------------------------------------------------------------------------
#define ROWS_PER_WG 64
__global__ __launch_bounds__(256, 2) void out_proj(
    const float* __restrict__ Wout, const float* __restrict__ bout,
    const int* __restrict__ Np, float* __restrict__ out)
{
    const int N = *Np;
    const size_t rows_total = (size_t)B_ * N;          // multiple of 64 (B=64)
    const size_t r0 = (size_t)blockIdx.x * ROWS_PER_WG;
    if (r0 >= rows_total) return;
    const int tid = threadIdx.x;

    __shared__ __align__(16) float hrow[ROWS_PER_WG][DOUT];  // 64 KiB
    #pragma unroll 4
    for (int r = 0; r < ROWS_PER_WG; ++r)
        hrow[r][tid] = out[(r0 + r) * DOUT + tid];
    __syncthreads();

    float acc[ROWS_PER_WG];
    #pragma unroll
    for (int r = 0; r < ROWS_PER_WG; ++r) acc[r] = 0.f;
    const float bb = bout[tid];

    for (int k = 0; k < DH; k += 4) {
        const float w0 = Wout[(size_t)(k + 0) * DOUT + tid];
        const float w1 = Wout[(size_t)(k + 1) * DOUT + tid];
        const float w2 = Wout[(size_t)(k + 2) * DOUT + tid];
        const float w3 = Wout[(size_t)(k + 3) * DOUT + tid];
        #pragma unroll
        for (int r = 0; r < ROWS_PER_WG; ++r) {
            const float4 hv = *(const float4*)&hrow[r][k];   // LDS b128 broadcast
            acc[r] += hv.x * w0 + hv.y * w1 + hv.z * w2 + hv.w * w3;
        }
    }

    // each WG exclusively owns rows r0..r0+63; per-thread reads are complete
    #pragma unroll 4
    for (int r = 0; r < ROWS_PER_WG; ++r)
        out[(r0 + r) * DOUT + tid] = sigmoidf_(acc[r] + bb);
}

extern "C" void kernel_launch(void* const* d_in, const int* in_sizes, int n_in,
                              void* d_out, int out_size, void* d_ws, size_t ws_size,
                              hipStream_t stream) {
    const float* x    = (const float*)d_in[0];
    const float* h0   = (const float*)d_in[1];
    const float* c0   = (const float*)d_in[2];
    const float* Wf   = (const float*)d_in[3];
    const float* bf   = (const float*)d_in[4];
    const float* Wi   = (const float*)d_in[5];
    const float* bi   = (const float*)d_in[6];
    const float* Wo   = (const float*)d_in[7];
    const float* bo   = (const float*)d_in[8];
    const float* Wout = (const float*)d_in[9];
    const float* bout = (const float*)d_in[10];
    const int*   Np   = (const int*)d_in[11];
    float* out = (float*)d_out;

    const int xT = in_sizes[0] / (B_ * DIN);   // time extent of the x buffer

    hipLaunchKernelGGL(lstm_rec, dim3(B_), dim3(1024), 0, stream,
                       x, h0, c0, Wf, bf, Wi, bi, Wo, bo, Np, out, xT);

    const int post_blocks = (B_ * T_) / ROWS_PER_WG;   // device-side guard handles N<T
    hipLaunchKernelGGL(out_proj, dim3(post_blocks), dim3(256), 0, stream,
                       Wout, bout, Np, out);
}

// Round 3
// 46460.855 us; speedup vs baseline: 3.5880x; 3.5880x over previous
//
#include <hip/hip_runtime.h>
#include <math.h>

// Problem constants (match reference)
#define B_    64
#define T_    2048
#define DIN   256
#define DH    256
#define DC    256
#define DOUT  256

__device__ __forceinline__ float sigmoidf_(float x) {
    return 1.0f / (1.0f + __expf(-x));
}

__device__ __forceinline__ float tanhf_(float x) {
    float ax = fabsf(x);
    float e  = __expf(-2.0f * ax);
    float t  = (1.0f - e) / (1.0f + e);
    return copysignf(t, x);
}

// ---------------------------------------------------------------------------
// Column-split persistent recurrent kernel.
// 64 WGs x 512 threads. WG w owns gate columns [4w, 4w+4) of f/i/o for ALL
// 64 batches. lane = batch, wave = k-slice (64 of 512 k's per wave).
// - Weights: read via wave-uniform (readfirstlane) addresses -> scalar/L1
//   path, 24 KB/WG working set, never re-streamed from L2 at volume.
// - h exchange: transposed hbuf[2][256][64] in d_ws via agent-scope atomics
//   (coherent point; per-XCD L2s are not cross-coherent). No __threadfence,
//   so L1/L2 keep weights + x hot.
// - Barrier: monotonic device counter, 1 arrival/WG/step. 64 WGs are always
//   co-resident (<< 256 CUs) so spin-wait cannot deadlock.
// - Gate preacts: reduced across the 8 k-waves by LDS atomicAdd into a
//   bias-pre-initialized part[12][64] (3 KB LDS total).
// Output projection deferred to out_proj (validated in round 2).
// ---------------------------------------------------------------------------
__global__ __launch_bounds__(512, 1) void lstm_rec(
    const float* __restrict__ x,  const float* __restrict__ h0,
    const float* __restrict__ c0, const float* __restrict__ Wf,
    const float* __restrict__ bf, const float* __restrict__ Wi,
    const float* __restrict__ bi, const float* __restrict__ Wo,
    const float* __restrict__ bo, const int* __restrict__ Np,
    float* __restrict__ out, int* __restrict__ ctr,
    float* __restrict__ hbuf,   // [2][256][64] floats
    int xT)
{
    const int tid = threadIdx.x;
    const int w   = blockIdx.x;
    const int b   = tid & 63;                                  // batch lane
    const int ks  = __builtin_amdgcn_readfirstlane(tid >> 6);  // wave id 0..7
    const int N   = *Np;
    const int wbase = w * 4;

    __shared__ float part[12][64];   // [gate*4 + c'][b] preacts (bias-seeded)

    // gate-state threads: tid < 256, c' = wave id (0..3), batch = b
    const int cp  = ks;              // valid as c' only when tid < 256
    const int col = wbase + cp;
    float c_state = 0.f, h_last = 0.f, bfv = 0.f, biv = 0.f, bov = 0.f;
    if (tid < 256) {
        c_state = c0[b * DC + col];
        bfv = bf[col]; biv = bi[col]; bov = bo[col];
        part[0 + cp][b] = bfv;       // seed preacts with biases
        part[4 + cp][b] = biv;
        part[8 + cp][b] = bov;
    }
    __syncthreads();

    // float4 views of weight rows at this WG's column base (16B aligned)
    const float4* wf4 = (const float4*)(Wf + wbase);
    const float4* wi4 = (const float4*)(Wi + wbase);
    const float4* wo4 = (const float4*)(Wo + wbase);

    for (int t = 0; t < N; ++t) {
        // ---- issue x loads for this step before any waiting ----
        const size_t xoff = ((size_t)b * xT + t) * DIN + ks * 32;
        float4 xv[8];
        #pragma unroll
        for (int j = 0; j < 8; ++j)
            xv[j] = *(const float4*)(x + xoff + 4 * j);

        // ---- wait for h[t] from all WGs (t=0 reads h0 directly) ----
        if (t > 0) {
            if (tid == 0) {
                while (__hip_atomic_load(ctr, __ATOMIC_RELAXED,
                                         __HIP_MEMORY_SCOPE_AGENT) < 64 * t) {
                    __builtin_amdgcn_s_sleep(2);
                }
            }
            __syncthreads();
        }

        // ---- load this wave's 32 h values (k = 256 + ks*32 + j) ----
        float hv[32];
        if (t == 0) {
            #pragma unroll
            for (int j = 0; j < 32; ++j)
                hv[j] = h0[b * DH + ks * 32 + j];       // one-time gather
        } else {
            const float* hb = hbuf + (size_t)(t & 1) * (DH * 64);
            #pragma unroll
            for (int j = 0; j < 32; ++j)                 // coalesced, agent-scope
                hv[j] = __hip_atomic_load(hb + (ks * 32 + j) * 64 + b,
                                          __ATOMIC_RELAXED,
                                          __HIP_MEMORY_SCOPE_AGENT);
        }

        // ---- FMA: x-part (k = ks*32 + kk) ----
        float4 accf = {0,0,0,0}, acci = {0,0,0,0}, acco = {0,0,0,0};
        #pragma unroll
        for (int kk = 0; kk < 32; ++kk) {
            const size_t k = (size_t)(ks * 32 + kk);
            const float  cv = ((const float*)xv)[kk];
            const float4 wfv = wf4[k * 64];   // uniform addr -> scalar path
            const float4 wiv = wi4[k * 64];
            const float4 wov = wo4[k * 64];
            accf.x += cv*wfv.x; accf.y += cv*wfv.y; accf.z += cv*wfv.z; accf.w += cv*wfv.w;
            acci.x += cv*wiv.x; acci.y += cv*wiv.y; acci.z += cv*wiv.z; acci.w += cv*wiv.w;
            acco.x += cv*wov.x; acco.y += cv*wov.y; acco.z += cv*wov.z; acco.w += cv*wov.w;
        }
        // ---- FMA: h-part (k = 256 + ks*32 + kk) ----
        #pragma unroll
        for (int kk = 0; kk < 32; ++kk) {
            const size_t k = (size_t)(256 + ks * 32 + kk);
            const float  cv = hv[kk];
            const float4 wfv = wf4[k * 64];
            const float4 wiv = wi4[k * 64];
            const float4 wov = wo4[k * 64];
            accf.x += cv*wfv.x; accf.y += cv*wfv.y; accf.z += cv*wfv.z; accf.w += cv*wfv.w;
            acci.x += cv*wiv.x; acci.y += cv*wiv.y; acci.z += cv*wiv.z; acci.w += cv*wiv.w;
            acco.x += cv*wov.x; acco.y += cv*wov.y; acco.z += cv*wov.z; acco.w += cv*wov.w;
        }

        // ---- cross-wave reduction into bias-seeded part[][] ----
        #pragma unroll
        for (int q = 0; q < 4; ++q) {
            atomicAdd(&part[0 + q][b], ((const float*)&accf)[q]);
            atomicAdd(&part[4 + q][b], ((const float*)&acci)[q]);
            atomicAdd(&part[8 + q][b], ((const float*)&acco)[q]);
        }
        __syncthreads();

        // ---- gate math: threads (c'=cp, b), tid < 256 ----
        if (tid < 256) {
            const float fp = part[0 + cp][b];
            const float ip = part[4 + cp][b];
            const float op = part[8 + cp][b];
            // re-seed for next step (each slot owned by this thread)
            part[0 + cp][b] = bfv;
            part[4 + cp][b] = biv;
            part[8 + cp][b] = bov;
            const float f = sigmoidf_(fp);
            const float i = sigmoidf_(ip);
            const float z = tanhf_(ip);       // pre_i reused, per reference
            const float o = sigmoidf_(op);
            c_state = c_state * f + z * i;
            h_last  = tanhf_(c_state) * o;
            // raw h into out (projected in place later); L2 merges the 4B writes
            out[((size_t)b * N + t) * DOUT + col] = h_last;
            // publish h[t+1], transposed, agent scope
            __hip_atomic_store(hbuf + (size_t)((t + 1) & 1) * (DH * 64) + col * 64 + b,
                               h_last, __ATOMIC_RELAXED, __HIP_MEMORY_SCOPE_AGENT);
        }

        // make this WG's stores agent-visible, then arrive
        __builtin_amdgcn_fence(__ATOMIC_RELEASE, "agent");
        __syncthreads();
        if (tid == 0)
            __hip_atomic_fetch_add(ctr, 1, __ATOMIC_RELEASE, __HIP_MEMORY_SCOPE_AGENT);
    }

    // finals: d_out = [ outs (B*N*DOUT) | h_final (B*DH) | c_final (B*DC) ]
    if (tid < 256) {
        float* hf = out + (size_t)B_ * N * DOUT;
        float* cf = hf + (size_t)B_ * DH;
        hf[b * DH + col] = h_last;
        cf[b * DC + col] = c_state;
    }
}

// ---------------------------------------------------------------------------
// Output projection, in place on d_out: out[r,:] = sigmoid(h[r,:] @ Wout + bout)
// 64 rows per WG staged in LDS, 64 accumulators/thread. (Validated round 2.)
// ---------------------------------------------------------------------------
#define ROWS_PER_WG 64
__global__ __launch_bounds__(256, 2) void out_proj(
    const float* __restrict__ Wout, const float* __restrict__ bout,
    const int* __restrict__ Np, float* __restrict__ out)
{
    const int N = *Np;
    const size_t rows_total = (size_t)B_ * N;
    const size_t r0 = (size_t)blockIdx.x * ROWS_PER_WG;
    if (r0 >= rows_total) return;
    const int tid = threadIdx.x;

    __shared__ __align__(16) float hrow[ROWS_PER_WG][DOUT];  // 64 KiB
    #pragma unroll 4
    for (int r = 0; r < ROWS_PER_WG; ++r)
        hrow[r][tid] = out[(r0 + r) * DOUT + tid];
    __syncthreads();

    float acc[ROWS_PER_WG];
    #pragma unroll
    for (int r = 0; r < ROWS_PER_WG; ++r) acc[r] = 0.f;
    const float bb = bout[tid];

    for (int k = 0; k < DH; k += 4) {
        const float w0 = Wout[(size_t)(k + 0) * DOUT + tid];
        const float w1 = Wout[(size_t)(k + 1) * DOUT + tid];
        const float w2 = Wout[(size_t)(k + 2) * DOUT + tid];
        const float w3 = Wout[(size_t)(k + 3) * DOUT + tid];
        #pragma unroll
        for (int r = 0; r < ROWS_PER_WG; ++r) {
            const float4 hv = *(const float4*)&hrow[r][k];
            acc[r] += hv.x * w0 + hv.y * w1 + hv.z * w2 + hv.w * w3;
        }
    }

    #pragma unroll 4
    for (int r = 0; r < ROWS_PER_WG; ++r)
        out[(r0 + r) * DOUT + tid] = sigmoidf_(acc[r] + bb);
}

extern "C" void kernel_launch(void* const* d_in, const int* in_sizes, int n_in,
                              void* d_out, int out_size, void* d_ws, size_t ws_size,
                              hipStream_t stream) {
    const float* x    = (const float*)d_in[0];
    const float* h0   = (const float*)d_in[1];
    const float* c0   = (const float*)d_in[2];
    const float* Wf   = (const float*)d_in[3];
    const float* bf   = (const float*)d_in[4];
    const float* Wi   = (const float*)d_in[5];
    const float* bi   = (const float*)d_in[6];
    const float* Wo   = (const float*)d_in[7];
    const float* bo   = (const float*)d_in[8];
    const float* Wout = (const float*)d_in[9];
    const float* bout = (const float*)d_in[10];
    const int*   Np   = (const int*)d_in[11];
    float* out = (float*)d_out;

    const int xT = in_sizes[0] / (B_ * DIN);   // time extent of x buffer

    // ws layout: [0,256): barrier counter (zeroed every launch; ws is
    // re-poisoned to 0xAA by the harness). [256, 256+128KiB): hbuf[2][256][64].
    int*   ctr  = (int*)d_ws;
    float* hbuf = (float*)((char*)d_ws + 256);
    hipMemsetAsync(d_ws, 0, 256, stream);

    hipLaunchKernelGGL(lstm_rec, dim3(64), dim3(512), 0, stream,
                       x, h0, c0, Wf, bf, Wi, bi, Wo, bo, Np, out, ctr, hbuf, xT);

    const int post_blocks = (B_ * T_) / ROWS_PER_WG;   // device-side guard handles N<T
    hipLaunchKernelGGL(out_proj, dim3(post_blocks), dim3(256), 0, stream,
                       Wout, bout, Np, out);
}